// Round 1
// baseline (860.316 us; speedup 1.0000x reference)
//
#include <hip/hip_runtime.h>
#include <math.h>

#define B_    8
#define C_    256
#define N_    16384
#define H_    4
#define D_    32
#define HID_  128
#define ROWS_ 384
#define SCALE 0.17677669529663687f   // 32^-0.5

// ------------------------------------------------------------------
// Kernel 1: qkv GEMM + q-softmax(->ws) + exp(k) + context partials
// ------------------------------------------------------------------
#define TN   64
#define KCH  32
#define WPAD (ROWS_ + 4)   // 388, keeps float4 alignment, breaks bank stride

__global__ __launch_bounds__(256, 2) void k_qkv(
    const float* __restrict__ x, const float* __restrict__ wqkv,
    float* __restrict__ qt, float* __restrict__ ctxacc)
{
    // union'd LDS: GEMM stage = KCH*TN + KCH*WPAD = 14464 floats
    //              epilogue ekv = 256*68 = 17408 floats  -> 68 KiB
    __shared__ float smem[17408];
    float* xs = smem;              // [KCH][TN]
    float* wt = smem + KCH * TN;   // [KCH][WPAD]

    const int blk  = blockIdx.x;
    const int b    = blk / (N_ / TN);
    const int n0   = (blk % (N_ / TN)) * TN;
    const int t    = threadIdx.x;
    const int lane = t & 63;
    const int wv   = t >> 6;
    const int rg   = t >> 3;   // 0..31 -> rows rg*12 .. +12
    const int cg   = t & 7;    // cols cg*8 .. +8

    float acc[12][8];
#pragma unroll
    for (int i = 0; i < 12; i++)
#pragma unroll
        for (int j = 0; j < 8; j++) acc[i][j] = 0.f;

    for (int kc = 0; kc < C_; kc += KCH) {
        // stage x chunk: xs[kk][col], coalesced
#pragma unroll
        for (int i = 0; i < 8; i++) {
            int kk = wv * 8 + i;
            xs[kk * TN + lane] = x[((size_t)b * C_ + kc + kk) * N_ + n0 + lane];
        }
        // stage w chunk transposed: wt[kk][row], coalesced over kk
        for (int i = 0; i < 48; i++) {
            int lin = i * 256 + t;
            int row = lin >> 5;
            int kk  = lin & 31;
            wt[kk * WPAD + row] = wqkv[row * C_ + kc + kk];
        }
        __syncthreads();
#pragma unroll 4
        for (int kk = 0; kk < KCH; kk++) {
            const float4* wr = reinterpret_cast<const float4*>(&wt[kk * WPAD + rg * 12]);
            float4 w0 = wr[0], w1 = wr[1], w2 = wr[2];
            const float4* xr = reinterpret_cast<const float4*>(&xs[kk * TN + cg * 8]);
            float4 x0 = xr[0], x1 = xr[1];
            float wa[12] = {w0.x,w0.y,w0.z,w0.w, w1.x,w1.y,w1.z,w1.w, w2.x,w2.y,w2.z,w2.w};
            float xa[8]  = {x0.x,x0.y,x0.z,x0.w, x1.x,x1.y,x1.z,x1.w};
#pragma unroll
            for (int i = 0; i < 12; i++)
#pragma unroll
                for (int j = 0; j < 8; j++)
                    acc[i][j] = fmaf(wa[i], xa[j], acc[i][j]);
        }
        __syncthreads();
    }

    // ---- epilogue 1: q rows (0..127) -> LDS, softmax over d, write q~ ----
    float* qbuf = smem;  // [128][68]
#pragma unroll
    for (int i = 0; i < 12; i++) {
        int grow = rg * 12 + i;
        if (grow < HID_) {
#pragma unroll
            for (int j = 0; j < 8; j++) qbuf[grow * 68 + cg * 8 + j] = acc[i][j];
        }
    }
    __syncthreads();
    {
        int h = t >> 6, col = t & 63;
        float vals[32];
        float mx = -1e30f;
#pragma unroll
        for (int d = 0; d < 32; d++) { vals[d] = qbuf[(h * 32 + d) * 68 + col]; mx = fmaxf(mx, vals[d]); }
        float s = 0.f;
#pragma unroll
        for (int d = 0; d < 32; d++) { vals[d] = __expf(vals[d] - mx); s += vals[d]; }
        float inv = SCALE / s;
#pragma unroll
        for (int d = 0; d < 32; d++)
            qt[((size_t)b * HID_ + h * 32 + d) * N_ + n0 + col] = vals[d] * inv;
    }
    __syncthreads();

    // ---- epilogue 2: exp(k) rows and v rows -> LDS ----
    float* ekv = smem;  // [256][68]: rows 0..127 = exp(k), 128..255 = v
#pragma unroll
    for (int i = 0; i < 12; i++) {
        int grow = rg * 12 + i;
        if (grow >= HID_) {
            int r = grow - HID_;
#pragma unroll
            for (int j = 0; j < 8; j++) {
                float v = acc[i][j];
                ekv[r * 68 + cg * 8 + j] = (r < HID_) ? __expf(v) : v;
            }
        }
    }
    __syncthreads();

    // ---- epilogue 3: context partials (unnormalized) + denominator ----
    for (int e = t; e < H_ * D_ * (D_ + 1); e += 256) {
        int h   = e / (D_ * (D_ + 1));
        int rem = e % (D_ * (D_ + 1));
        int d   = rem / (D_ + 1);
        int j   = rem % (D_ + 1);
        const float4* ekr = reinterpret_cast<const float4*>(&ekv[(h * 32 + d) * 68]);
        float s = 0.f;
        if (j < D_) {
            const float4* vr = reinterpret_cast<const float4*>(&ekv[(HID_ + h * 32 + j) * 68]);
#pragma unroll 4
            for (int c4 = 0; c4 < TN / 4; c4++) {
                float4 a = ekr[c4], v = vr[c4];
                s = fmaf(a.x, v.x, s); s = fmaf(a.y, v.y, s);
                s = fmaf(a.z, v.z, s); s = fmaf(a.w, v.w, s);
            }
        } else {
#pragma unroll 4
            for (int c4 = 0; c4 < TN / 4; c4++) {
                float4 a = ekr[c4];
                s += a.x + a.y + a.z + a.w;
            }
        }
        atomicAdd(&ctxacc[((b * H_ + h) * D_ + d) * (D_ + 1) + j], s);
    }
}

// ------------------------------------------------------------------
// Kernel 2: finalize ctx, hidden = ctx^T @ q~, y = w_out@hidden + b,
//           RMSNorm over c, store
// ------------------------------------------------------------------
#define TN2 64

__global__ __launch_bounds__(256, 2) void k_out(
    const float* __restrict__ qt, const float* __restrict__ ctxacc,
    const float* __restrict__ wout, const float* __restrict__ bout,
    const float* __restrict__ g, float* __restrict__ out)
{
    __shared__ float ctxf[H_ * D_ * D_];  // [h][d][e]
    __shared__ float hb[HID_][68];        // hidden tile
    __shared__ float wob[16][C_];         // w_out chunk transposed [ee][c]
    __shared__ float red[32][65];
    __shared__ float nrm[64];

    const int blk  = blockIdx.x;
    const int b    = blk / (N_ / TN2);
    const int n0   = (blk % (N_ / TN2)) * TN2;
    const int t    = threadIdx.x;
    const int lane = t & 63;
    const int wv   = t >> 6;

    // finalize context: ctxf = unnorm / denom
    for (int e2 = t; e2 < H_ * D_ * D_; e2 += 256) {
        int h = e2 >> 10, d = (e2 >> 5) & 31, j = e2 & 31;
        const float* base = &ctxacc[((b * H_ + h) * D_ + d) * (D_ + 1)];
        ctxf[e2] = base[j] / base[32];
    }

    // load q~ column into regs: wave wv owns head wv, lane = col
    float qv[32];
#pragma unroll
    for (int d = 0; d < 32; d++)
        qv[d] = qt[((size_t)b * HID_ + wv * 32 + d) * N_ + n0 + lane];
    __syncthreads();

    // hidden[e] = sum_d ctx[d][e] * q~[d]
    float hacc[32];
#pragma unroll
    for (int e = 0; e < 32; e++) hacc[e] = 0.f;
#pragma unroll 4
    for (int d = 0; d < 32; d++) {
        const float4* cr = reinterpret_cast<const float4*>(&ctxf[(wv * 32 + d) * 32]);
        float q = qv[d];
#pragma unroll
        for (int e4 = 0; e4 < 8; e4++) {
            float4 c = cr[e4];
            hacc[e4*4+0] = fmaf(c.x, q, hacc[e4*4+0]);
            hacc[e4*4+1] = fmaf(c.y, q, hacc[e4*4+1]);
            hacc[e4*4+2] = fmaf(c.z, q, hacc[e4*4+2]);
            hacc[e4*4+3] = fmaf(c.w, q, hacc[e4*4+3]);
        }
    }
#pragma unroll
    for (int e = 0; e < 32; e++) hb[wv * 32 + e][lane] = hacc[e];
    __syncthreads();

    // w_out GEMM, 8x8 register blocking: wave wv -> c rows wv*64..+64
    const int cg2 = lane >> 3, colg = lane & 7;
    const int cbase = wv * 64 + cg2 * 8;
    float yacc[8][8];
#pragma unroll
    for (int i = 0; i < 8; i++)
#pragma unroll
        for (int j = 0; j < 8; j++) yacc[i][j] = 0.f;

    for (int ec = 0; ec < HID_; ec += 16) {
        __syncthreads();
        for (int i = 0; i < 16; i++) {
            int lin = i * 256 + t;
            int c = lin >> 4, ee = lin & 15;
            wob[ee][c] = wout[c * HID_ + ec + ee];
        }
        __syncthreads();
#pragma unroll 4
        for (int ee = 0; ee < 16; ee++) {
            const float4* wr = reinterpret_cast<const float4*>(&wob[ee][cbase]);
            float4 w0 = wr[0], w1 = wr[1];
            const float4* hr = reinterpret_cast<const float4*>(&hb[ec + ee][colg * 8]);
            float4 h0 = hr[0], h1 = hr[1];
            float wa[8] = {w0.x,w0.y,w0.z,w0.w, w1.x,w1.y,w1.z,w1.w};
            float ha[8] = {h0.x,h0.y,h0.z,h0.w, h1.x,h1.y,h1.z,h1.w};
#pragma unroll
            for (int i = 0; i < 8; i++)
#pragma unroll
                for (int j = 0; j < 8; j++)
                    yacc[i][j] = fmaf(wa[i], ha[j], yacc[i][j]);
        }
    }

    // bias
#pragma unroll
    for (int i = 0; i < 8; i++) {
        float bo = bout[cbase + i];
#pragma unroll
        for (int j = 0; j < 8; j++) yacc[i][j] += bo;
    }

    // RMS norm over c (256 rows spread over 32 thread-groups)
#pragma unroll
    for (int j = 0; j < 8; j++) {
        float s = 0.f;
#pragma unroll
        for (int i = 0; i < 8; i++) s = fmaf(yacc[i][j], yacc[i][j], s);
        red[wv * 8 + cg2][colg * 8 + j] = s;
    }
    __syncthreads();
    if (t < 64) {
        float s = 0.f;
#pragma unroll
        for (int i = 0; i < 32; i++) s += red[i][t];
        nrm[t] = 16.0f / fmaxf(sqrtf(s), 1e-12f);
    }
    __syncthreads();

#pragma unroll
    for (int i = 0; i < 8; i++) {
        int c = cbase + i;
        float gc = g[c];
        float ov[8];
#pragma unroll
        for (int j = 0; j < 8; j++) ov[j] = yacc[i][j] * gc * nrm[colg * 8 + j];
        float4* op = reinterpret_cast<float4*>(&out[((size_t)b * C_ + c) * N_ + n0 + colg * 8]);
        op[0] = *reinterpret_cast<float4*>(&ov[0]);
        op[1] = *reinterpret_cast<float4*>(&ov[4]);
    }
}

// ------------------------------------------------------------------
extern "C" void kernel_launch(void* const* d_in, const int* in_sizes, int n_in,
                              void* d_out, int out_size, void* d_ws, size_t ws_size,
                              hipStream_t stream)
{
    const float* x    = (const float*)d_in[0];
    const float* wqkv = (const float*)d_in[1];
    const float* wout = (const float*)d_in[2];
    const float* bout = (const float*)d_in[3];
    const float* g    = (const float*)d_in[4];
    float* out = (float*)d_out;

    float* qt     = (float*)d_ws;                        // [B][HID][N] = 64 MiB
    float* ctxacc = qt + (size_t)B_ * HID_ * N_;         // [B][H][D][D+1]

    hipMemsetAsync(ctxacc, 0, (size_t)B_ * H_ * D_ * (D_ + 1) * sizeof(float), stream);
    k_qkv<<<B_ * (N_ / TN), 256, 0, stream>>>(x, wqkv, qt, ctxacc);
    k_out<<<B_ * (N_ / TN2), 256, 0, stream>>>(qt, ctxacc, wout, bout, g, out);
}

// Round 2
// 394.068 us; speedup vs baseline: 2.1832x; 2.1832x over previous
//
#include <hip/hip_runtime.h>
#include <hip/hip_bf16.h>
#include <math.h>

#define B_    8
#define C_    256
#define N_    16384
#define H_    4
#define D_    32
#define HID_  128
#define ROWS_ 384
#define SCALE 0.17677669529663687f   // 32^-0.5

typedef __attribute__((ext_vector_type(8))) short bf16x8;
typedef __attribute__((ext_vector_type(16))) float f32x16;

__device__ __forceinline__ short f2bf(float f) {
    union { __hip_bfloat16 h; short s; } u;
    u.h = __float2bfloat16(f);
    return u.s;
}

// ------------------------------------------------------------------
// Kernel 0: convert w_qkv fp32 -> bf16 (row-major [384][256])
// ------------------------------------------------------------------
__global__ void k_conv(const float* __restrict__ w, short* __restrict__ wb)
{
    int i = (blockIdx.x * 256 + threadIdx.x) * 4;
    float4 f = *reinterpret_cast<const float4*>(w + i);
    short4 s;
    s.x = f2bf(f.x); s.y = f2bf(f.y); s.z = f2bf(f.z); s.w = f2bf(f.w);
    *reinterpret_cast<short4*>(wb + i) = s;
}

// ------------------------------------------------------------------
// Kernel 1: qkv GEMM via bf16 MFMA + q-softmax(->bf16 ws) + exp(k)
//           + context partials (atomics)
// Block: 256 threads (4 waves), 64 columns of n, all 384 rows.
// Wave wv owns row-tiles {wv, wv+4, wv+8} == {q,k,v} of head wv.
// ------------------------------------------------------------------
__global__ __launch_bounds__(256, 2) void k_qkv(
    const float* __restrict__ x, const short* __restrict__ wbf,
    __hip_bfloat16* __restrict__ qtb, float* __restrict__ ctxacc)
{
    __shared__ float ekv_s[4][2][32][68];   // [wave][ek/v][row][col] = 68 KiB

    const int blk = blockIdx.x;
    const int b   = blk >> 8;            // N/64 = 256 col-blocks per batch
    const int n0  = (blk & 255) << 6;
    const int t   = threadIdx.x;
    const int l   = t & 63;
    const int wv  = t >> 6;
    const int c31 = l & 31;
    const int hf  = l >> 5;

    f32x16 acc[3][2];
#pragma unroll
    for (int ti = 0; ti < 3; ti++)
#pragma unroll
        for (int ct = 0; ct < 2; ct++)
#pragma unroll
            for (int r = 0; r < 16; r++) acc[ti][ct][r] = 0.f;

    const float* xbase = x + (size_t)b * C_ * N_ + n0 + c31;

    // ---- K loop: 16 MFMA k-steps of 16 ----
    for (int ks = 0; ks < 16; ks++) {
        const int k0 = ks * 16 + hf * 8;
        // B fragments: x[k0..k0+7][n0 + ct*32 + c31], fp32 -> bf16
        bf16x8 bfr[2];
#pragma unroll
        for (int ct = 0; ct < 2; ct++) {
            const float* xp = xbase + (size_t)k0 * N_ + ct * 32;
#pragma unroll
            for (int i = 0; i < 8; i++)
                bfr[ct][i] = f2bf(xp[(size_t)i * N_]);
        }
        // A fragments (bf16 w, contiguous 16B) + MFMA
#pragma unroll
        for (int ti = 0; ti < 3; ti++) {
            const int row = (wv + ti * 4) * 32 + c31;
            bf16x8 af = *reinterpret_cast<const bf16x8*>(wbf + row * 256 + k0);
            acc[ti][0] = __builtin_amdgcn_mfma_f32_32x32x16_bf16(af, bfr[0], acc[ti][0], 0, 0, 0);
            acc[ti][1] = __builtin_amdgcn_mfma_f32_32x32x16_bf16(af, bfr[1], acc[ti][1], 0, 0, 0);
        }
    }

    // C layout (verified m74/m101): col = lane&31, row = (r&3)+8*(r>>2)+4*(lane>>5)

    // ---- q epilogue: softmax over d (16 regs + partner half-wave) ----
#pragma unroll
    for (int ct = 0; ct < 2; ct++) {
        float mx = -1e30f;
#pragma unroll
        for (int r = 0; r < 16; r++) mx = fmaxf(mx, acc[0][ct][r]);
        mx = fmaxf(mx, __shfl_xor(mx, 32));
        float e[16]; float s = 0.f;
#pragma unroll
        for (int r = 0; r < 16; r++) { e[r] = __expf(acc[0][ct][r] - mx); s += e[r]; }
        s += __shfl_xor(s, 32);
        float inv = SCALE / s;
        __hip_bfloat16* qp = qtb + ((size_t)b * HID_ + wv * 32) * N_ + n0 + ct * 32 + c31;
#pragma unroll
        for (int r = 0; r < 16; r++) {
            int rm = (r & 3) + 8 * (r >> 2) + 4 * hf;
            qp[(size_t)rm * N_] = __float2bfloat16(e[r] * inv);
        }
    }

    // ---- k,v epilogue: exp(k) and v tiles -> LDS ----
#pragma unroll
    for (int ct = 0; ct < 2; ct++)
#pragma unroll
        for (int r = 0; r < 16; r++) {
            int rm = (r & 3) + 8 * (r >> 2) + 4 * hf;
            ekv_s[wv][0][rm][ct * 32 + c31] = __expf(acc[1][ct][r]);
            ekv_s[wv][1][rm][ct * 32 + c31] = acc[2][ct][r];
        }
    __syncthreads();

    // ---- context partials: ctx[d][e] += sum_n ek[d,n]*v[e,n], 4x4 strided ----
    const int dB = l >> 3, eB = l & 7;   // d in dB+8i, e in eB+8j
    float cacc[4][4];
    float dden[4];
#pragma unroll
    for (int i = 0; i < 4; i++) {
        dden[i] = 0.f;
#pragma unroll
        for (int j = 0; j < 4; j++) cacc[i][j] = 0.f;
    }
    const float* ekp = &ekv_s[wv][0][0][0];
    const float* vvp = &ekv_s[wv][1][0][0];
#pragma unroll 4
    for (int cc = 0; cc < 16; cc++) {
        float4 ekr[4], vr[4];
#pragma unroll
        for (int i = 0; i < 4; i++)
            ekr[i] = *reinterpret_cast<const float4*>(ekp + (dB + 8 * i) * 68 + cc * 4);
#pragma unroll
        for (int j = 0; j < 4; j++)
            vr[j] = *reinterpret_cast<const float4*>(vvp + (eB + 8 * j) * 68 + cc * 4);
#pragma unroll
        for (int i = 0; i < 4; i++) {
#pragma unroll
            for (int j = 0; j < 4; j++) {
                cacc[i][j] = fmaf(ekr[i].x, vr[j].x, cacc[i][j]);
                cacc[i][j] = fmaf(ekr[i].y, vr[j].y, cacc[i][j]);
                cacc[i][j] = fmaf(ekr[i].z, vr[j].z, cacc[i][j]);
                cacc[i][j] = fmaf(ekr[i].w, vr[j].w, cacc[i][j]);
            }
            if (eB == 0) dden[i] += ekr[i].x + ekr[i].y + ekr[i].z + ekr[i].w;
        }
    }
    float* cb = ctxacc + (size_t)(b * H_ + wv) * D_ * 33;
#pragma unroll
    for (int i = 0; i < 4; i++) {
#pragma unroll
        for (int j = 0; j < 4; j++)
            atomicAdd(cb + (dB + 8 * i) * 33 + (eB + 8 * j), cacc[i][j]);
        if (eB == 0) atomicAdd(cb + (dB + 8 * i) * 33 + 32, dden[i]);
    }
}

// ------------------------------------------------------------------
// Kernel 2: finalize ctx, hidden = ctx^T @ q~, y = w_out@hidden + b,
//           RMSNorm over c, store   (q~ now bf16)
// ------------------------------------------------------------------
#define TN2 64

__global__ __launch_bounds__(256, 2) void k_out(
    const __hip_bfloat16* __restrict__ qtb, const float* __restrict__ ctxacc,
    const float* __restrict__ wout, const float* __restrict__ bout,
    const float* __restrict__ g, float* __restrict__ out)
{
    __shared__ float ctxf[H_ * D_ * D_];  // [h][d][e]
    __shared__ float hb[HID_][68];        // hidden tile
    __shared__ float wob[16][C_];         // w_out chunk transposed [ee][c]
    __shared__ float red[32][65];
    __shared__ float nrm[64];

    const int blk  = blockIdx.x;
    const int b    = blk / (N_ / TN2);
    const int n0   = (blk % (N_ / TN2)) * TN2;
    const int t    = threadIdx.x;
    const int lane = t & 63;
    const int wv   = t >> 6;

    // finalize context: ctxf = unnorm / denom
    for (int e2 = t; e2 < H_ * D_ * D_; e2 += 256) {
        int h = e2 >> 10, d = (e2 >> 5) & 31, j = e2 & 31;
        const float* base = &ctxacc[((b * H_ + h) * D_ + d) * (D_ + 1)];
        ctxf[e2] = base[j] / base[32];
    }

    // load q~ column into regs: wave wv owns head wv, lane = col
    float qv[32];
#pragma unroll
    for (int d = 0; d < 32; d++)
        qv[d] = __bfloat162float(qtb[((size_t)b * HID_ + wv * 32 + d) * N_ + n0 + lane]);
    __syncthreads();

    // hidden[e] = sum_d ctx[d][e] * q~[d]
    float hacc[32];
#pragma unroll
    for (int e = 0; e < 32; e++) hacc[e] = 0.f;
#pragma unroll 4
    for (int d = 0; d < 32; d++) {
        const float4* cr = reinterpret_cast<const float4*>(&ctxf[(wv * 32 + d) * 32]);
        float q = qv[d];
#pragma unroll
        for (int e4 = 0; e4 < 8; e4++) {
            float4 c = cr[e4];
            hacc[e4*4+0] = fmaf(c.x, q, hacc[e4*4+0]);
            hacc[e4*4+1] = fmaf(c.y, q, hacc[e4*4+1]);
            hacc[e4*4+2] = fmaf(c.z, q, hacc[e4*4+2]);
            hacc[e4*4+3] = fmaf(c.w, q, hacc[e4*4+3]);
        }
    }
#pragma unroll
    for (int e = 0; e < 32; e++) hb[wv * 32 + e][lane] = hacc[e];
    __syncthreads();

    // w_out GEMM, 8x8 register blocking: wave wv -> c rows wv*64..+64
    const int cg2 = lane >> 3, colg = lane & 7;
    const int cbase = wv * 64 + cg2 * 8;
    float yacc[8][8];
#pragma unroll
    for (int i = 0; i < 8; i++)
#pragma unroll
        for (int j = 0; j < 8; j++) yacc[i][j] = 0.f;

    for (int ec = 0; ec < HID_; ec += 16) {
        __syncthreads();
        for (int i = 0; i < 16; i++) {
            int lin = i * 256 + t;
            int c = lin >> 4, ee = lin & 15;
            wob[ee][c] = wout[c * HID_ + ec + ee];
        }
        __syncthreads();
#pragma unroll 4
        for (int ee = 0; ee < 16; ee++) {
            const float4* wr = reinterpret_cast<const float4*>(&wob[ee][cbase]);
            float4 w0 = wr[0], w1 = wr[1];
            const float4* hr = reinterpret_cast<const float4*>(&hb[ec + ee][colg * 8]);
            float4 h0 = hr[0], h1 = hr[1];
            float wa[8] = {w0.x,w0.y,w0.z,w0.w, w1.x,w1.y,w1.z,w1.w};
            float ha[8] = {h0.x,h0.y,h0.z,h0.w, h1.x,h1.y,h1.z,h1.w};
#pragma unroll
            for (int i = 0; i < 8; i++)
#pragma unroll
                for (int j = 0; j < 8; j++)
                    yacc[i][j] = fmaf(wa[i], ha[j], yacc[i][j]);
        }
    }

    // bias
#pragma unroll
    for (int i = 0; i < 8; i++) {
        float bo = bout[cbase + i];
#pragma unroll
        for (int j = 0; j < 8; j++) yacc[i][j] += bo;
    }

    // RMS norm over c (256 rows spread over 32 thread-groups)
#pragma unroll
    for (int j = 0; j < 8; j++) {
        float s = 0.f;
#pragma unroll
        for (int i = 0; i < 8; i++) s = fmaf(yacc[i][j], yacc[i][j], s);
        red[wv * 8 + cg2][colg * 8 + j] = s;
    }
    __syncthreads();
    if (t < 64) {
        float s = 0.f;
#pragma unroll
        for (int i = 0; i < 32; i++) s += red[i][t];
        nrm[t] = 16.0f / fmaxf(sqrtf(s), 1e-12f);
    }
    __syncthreads();

#pragma unroll
    for (int i = 0; i < 8; i++) {
        int c = cbase + i;
        float gc = g[c];
        float ov[8];
#pragma unroll
        for (int j = 0; j < 8; j++) ov[j] = yacc[i][j] * gc * nrm[colg * 8 + j];
        float4* op = reinterpret_cast<float4*>(&out[((size_t)b * C_ + c) * N_ + n0 + colg * 8]);
        op[0] = *reinterpret_cast<float4*>(&ov[0]);
        op[1] = *reinterpret_cast<float4*>(&ov[4]);
    }
}

// ------------------------------------------------------------------
extern "C" void kernel_launch(void* const* d_in, const int* in_sizes, int n_in,
                              void* d_out, int out_size, void* d_ws, size_t ws_size,
                              hipStream_t stream)
{
    const float* x    = (const float*)d_in[0];
    const float* wqkv = (const float*)d_in[1];
    const float* wout = (const float*)d_in[2];
    const float* bout = (const float*)d_in[3];
    const float* g    = (const float*)d_in[4];
    float* out = (float*)d_out;

    // ws layout: qtb bf16 [B][HID][N] (32 MiB) | ctxacc f32 [B][H][D][33] | wbf bf16 [384*256]
    __hip_bfloat16* qtb = (__hip_bfloat16*)d_ws;
    float* ctxacc = (float*)((char*)d_ws + (size_t)B_ * HID_ * N_ * 2);
    short* wbf    = (short*)((char*)d_ws + (size_t)B_ * HID_ * N_ * 2
                             + (size_t)B_ * H_ * D_ * 33 * sizeof(float));

    hipMemsetAsync(ctxacc, 0, (size_t)B_ * H_ * D_ * 33 * sizeof(float), stream);
    k_conv<<<ROWS_ * C_ / (256 * 4), 256, 0, stream>>>(wqkv, wbf);
    k_qkv<<<B_ * (N_ / 64), 256, 0, stream>>>(x, wbf, qtb, ctxacc);
    k_out<<<B_ * (N_ / TN2), 256, 0, stream>>>(qtb, ctxacc, wout, bout, g, out);
}

// Round 3
// 192.370 us; speedup vs baseline: 4.4722x; 2.0485x over previous
//
#include <hip/hip_runtime.h>
#include <hip/hip_bf16.h>
#include <math.h>

#define B_    8
#define C_    256
#define N_    16384
#define H_    4
#define D_    32
#define HID_  128
#define ROWS_ 384
#define SCALE 0.17677669529663687f   // 32^-0.5

typedef __attribute__((ext_vector_type(8))) short bf16x8;
typedef __attribute__((ext_vector_type(16))) float f32x16;

__device__ __forceinline__ short f2bf(float f) {
    union { __hip_bfloat16 h; short s; } u;
    u.h = __float2bfloat16(f);
    return u.s;
}

// ------------------------------------------------------------------
// Kernel 0: convert w_qkv [384*256] and w_out [256*128] fp32 -> bf16
// into one contiguous buffer (wqkv first, wout after).
// ------------------------------------------------------------------
__global__ void k_conv(const float* __restrict__ wqkv, const float* __restrict__ wout,
                       short* __restrict__ wb)
{
    int i = (blockIdx.x * 256 + threadIdx.x) * 4;
    const float* src = (i < ROWS_ * C_) ? (wqkv + i) : (wout + (i - ROWS_ * C_));
    float4 f = *reinterpret_cast<const float4*>(src);
    short4 s;
    s.x = f2bf(f.x); s.y = f2bf(f.y); s.z = f2bf(f.z); s.w = f2bf(f.w);
    *reinterpret_cast<short4*>(wb + i) = s;
}

// ------------------------------------------------------------------
// Kernel 1: qkv GEMM (MFMA, LDS-staged swizzled x) + q-softmax
//           (-> bf16 q~ in [b][n][hid] layout, coalesced) + ctx
//           partials via MFMA on bf16 ek/v tiles (atomics).
// Block: 256 threads / 4 waves, 64 n-cols, all 384 rows.
// Wave wv owns row-tiles {wv, wv+4, wv+8} = {q,k,v} of head wv.
// ------------------------------------------------------------------
__global__ __launch_bounds__(256, 2) void k_qkv(
    const float* __restrict__ x, const short* __restrict__ wbf,
    short* __restrict__ qtb, float* __restrict__ ctxacc)
{
    __shared__ __align__(16) char smA[32768];  // phase1: x bf16 [64 n][256 k] swz16B
                                               // phase2: per-wave ek/v [32][64] bf16 swz16B
    __shared__ __align__(16) char smQ[16384];  // q~ staging [64 n][128 d] bf16 swz8B

    const int blk = blockIdx.x;
    const int b   = blk >> 8;              // 256 col-blocks per batch
    const int n0  = (blk & 255) << 6;
    const int t   = threadIdx.x;
    const int l   = t & 63;
    const int wv  = t >> 6;
    const int c31 = l & 31;
    const int hf  = l >> 5;

    // ---- stage x tile [256 k][64 n] -> bf16 transposed swizzled [n][k] ----
    {
        const int kg = t >> 4;             // 0..15
        const int n4 = (t & 15) * 4;
#pragma unroll
        for (int it = 0; it < 4; it++) {
            const int k = it * 64 + kg * 4;
            const float* xp = x + (size_t)b * C_ * N_ + (size_t)k * N_ + n0 + n4;
            float4 r0 = *(const float4*)(xp);
            float4 r1 = *(const float4*)(xp + N_);
            float4 r2 = *(const float4*)(xp + 2 * (size_t)N_);
            float4 r3 = *(const float4*)(xp + 3 * (size_t)N_);
#define WRT(J, FLD) { short4 sv; sv.x = f2bf(r0.FLD); sv.y = f2bf(r1.FLD); \
    sv.z = f2bf(r2.FLD); sv.w = f2bf(r3.FLD); \
    int n_ = n4 + J; int ad_ = n_ * 512 + ((2 * k) ^ ((n_ & 31) << 4)); \
    *(short4*)(smA + ad_) = sv; }
            WRT(0, x) WRT(1, y) WRT(2, z) WRT(3, w)
#undef WRT
        }
    }
    __syncthreads();

    // ---- MFMA K-loop: 16 k-steps of 16 ----
    f32x16 acc[3][2];
#pragma unroll
    for (int ti = 0; ti < 3; ti++)
#pragma unroll
        for (int ct = 0; ct < 2; ct++)
#pragma unroll
            for (int r = 0; r < 16; r++) acc[ti][ct][r] = 0.f;

#pragma unroll
    for (int ks = 0; ks < 16; ks++) {
        const int k0   = ks * 16 + hf * 8;
        const int slot = 2 * ks + hf;
        // n&31 == c31 for both ct tiles
        bf16x8 bfr0 = *(const bf16x8*)(smA + (c31)      * 512 + 16 * (slot ^ c31));
        bf16x8 bfr1 = *(const bf16x8*)(smA + (c31 + 32) * 512 + 16 * (slot ^ c31));
#pragma unroll
        for (int ti = 0; ti < 3; ti++) {
            const int row = (wv + ti * 4) * 32 + c31;
            bf16x8 af = *(const bf16x8*)(wbf + row * C_ + k0);
            acc[ti][0] = __builtin_amdgcn_mfma_f32_32x32x16_bf16(af, bfr0, acc[ti][0], 0, 0, 0);
            acc[ti][1] = __builtin_amdgcn_mfma_f32_32x32x16_bf16(af, bfr1, acc[ti][1], 0, 0, 0);
        }
    }
    __syncthreads();   // smA reads done; about to be overwritten

    // C layout: col = lane&31, row = (r&3)+8*(r>>2)+4*hf  (verified)

    // ---- q epilogue: softmax over d -> smQ (transposed, 8B-swizzled) ----
#pragma unroll
    for (int ct = 0; ct < 2; ct++) {
        float mx = -1e30f;
#pragma unroll
        for (int r = 0; r < 16; r++) mx = fmaxf(mx, acc[0][ct][r]);
        mx = fmaxf(mx, __shfl_xor(mx, 32));
        float e[16]; float s = 0.f;
#pragma unroll
        for (int r = 0; r < 16; r++) { e[r] = __expf(acc[0][ct][r] - mx); s += e[r]; }
        s += __shfl_xor(s, 32);
        float inv = SCALE / s;
        const int n = ct * 32 + c31;
#pragma unroll
        for (int r = 0; r < 16; r++) {
            int rm = (r & 3) + 8 * (r >> 2) + 4 * hf;
            int gq = (wv * 32 + rm) >> 2;            // 8B granule index 0..31
            int ad = n * 256 + 8 * (gq ^ (n & 31)) + ((2 * rm) & 7);
            *(short*)(smQ + ad) = f2bf(e[r] * inv);
        }
    }

    // ---- k,v epilogue: exp(k), v -> per-wave swizzled bf16 LDS tiles ----
    char* ekb = smA + wv * 8192;
    char* vvb = ekb + 4096;
#pragma unroll
    for (int ct = 0; ct < 2; ct++)
#pragma unroll
        for (int r = 0; r < 16; r++) {
            int rm = (r & 3) + 8 * (r >> 2) + 4 * hf;
            int n  = ct * 32 + c31;
            int ad = rm * 128 + ((2 * n) ^ ((rm & 7) << 4));
            *(short*)(ekb + ad) = f2bf(__expf(acc[1][ct][r]));
            *(short*)(vvb + ad) = f2bf(acc[2][ct][r]);
        }
    __syncthreads();

    // ---- coalesced q~ write: qtb[b][n0+n][128] ----
    {
        char* qdst = (char*)(qtb + ((size_t)b * N_ + n0) * HID_);
        const int nn  = t >> 4;
        const int c16 = t & 15;
#pragma unroll
        for (int p = 0; p < 4; p++) {
            int n  = p * 16 + nn;
            int g0 = c16 * 2;
            uint2 a0 = *(uint2*)(smQ + n * 256 + 8 * ((g0)     ^ (n & 31)));
            uint2 a1 = *(uint2*)(smQ + n * 256 + 8 * ((g0 + 1) ^ (n & 31)));
            uint4 val; val.x = a0.x; val.y = a0.y; val.z = a1.x; val.w = a1.y;
            *(uint4*)(qdst + n * 256 + c16 * 16) = val;
        }
    }

    // ---- ctx partials via MFMA: ctx[d][e] += sum_n ek[d,n] v[e,n] ----
    f32x16 cD, dD;
#pragma unroll
    for (int r = 0; r < 16; r++) { cD[r] = 0.f; dD[r] = 0.f; }
    bf16x8 ones;
#pragma unroll
    for (int i = 0; i < 8; i++) ones[i] = (short)0x3F80;   // bf16 1.0
#pragma unroll
    for (int ks = 0; ks < 4; ks++) {
        int slot = 2 * ks + hf;
        bf16x8 ea = *(const bf16x8*)(ekb + c31 * 128 + 16 * (slot ^ (c31 & 7)));
        bf16x8 vb = *(const bf16x8*)(vvb + c31 * 128 + 16 * (slot ^ (c31 & 7)));
        cD = __builtin_amdgcn_mfma_f32_32x32x16_bf16(ea, vb,   cD, 0, 0, 0);
        dD = __builtin_amdgcn_mfma_f32_32x32x16_bf16(ea, ones, dD, 0, 0, 0);
    }
    float* cb = ctxacc + (size_t)(b * H_ + wv) * D_ * 33;
#pragma unroll
    for (int r = 0; r < 16; r++) {
        int rm = (r & 3) + 8 * (r >> 2) + 4 * hf;
        atomicAdd(cb + rm * 33 + c31, cD[r]);
    }
    if (c31 == 0) {
#pragma unroll
        for (int r = 0; r < 16; r++) {
            int rm = (r & 3) + 8 * (r >> 2) + 4 * hf;
            atomicAdd(cb + rm * 33 + 32, dD[r]);
        }
    }
}

// ------------------------------------------------------------------
// Kernel 2: finalize ctx (->bf16 LDS), hidden = ctx^T @ q~ (MFMA),
//           y = w_out @ hidden (MFMA) + bias, RMSNorm over c, store.
// ------------------------------------------------------------------
__global__ __launch_bounds__(256, 3) void k_out(
    const short* __restrict__ qtb, const float* __restrict__ ctxacc,
    const short* __restrict__ woutb, const float* __restrict__ bout,
    const float* __restrict__ g, float* __restrict__ out)
{
    __shared__ __align__(16) short ctS[4 * 32 * 48];   // [h][e][d pad->48] bf16
    __shared__ __align__(16) char  hidS[16384];        // [n][128] bf16 swz16B
    __shared__ float gl[C_], bl[C_];
    __shared__ float red[4][64];
    __shared__ float nrm[64];

    const int blk = blockIdx.x;
    const int b   = blk >> 8;
    const int n0  = (blk & 255) << 6;
    const int t   = threadIdx.x;
    const int l   = t & 63;
    const int wv  = t >> 6;
    const int c31 = l & 31;
    const int hf  = l >> 5;

    gl[t] = g[t];
    bl[t] = bout[t];
    // finalize ctx -> ctS[h][e][d] (transposed, bf16)
    for (int idx = t; idx < 4096; idx += 256) {
        int h = idx >> 10, d = (idx >> 5) & 31, e = idx & 31;
        const float* base = ctxacc + (size_t)((b * H_ + h) * D_ + d) * 33;
        ctS[h * 1536 + e * 48 + d] = f2bf(base[e] / base[32]);
    }
    __syncthreads();

    // ---- hidden MFMA: wave wv -> head wv;  hid[e][n] = sum_d ctxT[e][d] q~[d][n]
    f32x16 hD[2];
#pragma unroll
    for (int ct = 0; ct < 2; ct++)
#pragma unroll
        for (int r = 0; r < 16; r++) hD[ct][r] = 0.f;
    const short* qb = qtb + ((size_t)b * N_ + n0) * HID_;
#pragma unroll
    for (int ks = 0; ks < 2; ks++) {
        int k0 = ks * 16 + hf * 8;
        bf16x8 af = *(const bf16x8*)(ctS + wv * 1536 + c31 * 48 + k0);
#pragma unroll
        for (int ct = 0; ct < 2; ct++) {
            bf16x8 bq = *(const bf16x8*)(qb + (size_t)(ct * 32 + c31) * HID_ + wv * 32 + k0);
            hD[ct] = __builtin_amdgcn_mfma_f32_32x32x16_bf16(af, bq, hD[ct], 0, 0, 0);
        }
    }
    // write hidden -> swizzled LDS [n][hfull]
#pragma unroll
    for (int ct = 0; ct < 2; ct++)
#pragma unroll
        for (int r = 0; r < 16; r++) {
            int rm = (r & 3) + 8 * (r >> 2) + 4 * hf;
            int hfull = wv * 32 + rm;
            int n = ct * 32 + c31;
            int ad = n * 256 + ((2 * hfull) ^ ((n & 15) << 4));
            *(short*)(hidS + ad) = f2bf(hD[ct][r]);
        }
    __syncthreads();

    // ---- w_out GEMM: wave wv -> c rows wv*64..+64 ----
    f32x16 yacc[2][2];
#pragma unroll
    for (int rt = 0; rt < 2; rt++)
#pragma unroll
        for (int ct = 0; ct < 2; ct++)
#pragma unroll
            for (int r = 0; r < 16; r++) yacc[rt][ct][r] = 0.f;

#pragma unroll
    for (int ks = 0; ks < 8; ks++) {
        int k0 = ks * 16 + hf * 8;
        int sx = 2 * ks + hf;
        bf16x8 bq0 = *(const bf16x8*)(hidS + (c31)      * 256 + 16 * (sx ^ (c31 & 15)));
        bf16x8 bq1 = *(const bf16x8*)(hidS + (c31 + 32) * 256 + 16 * (sx ^ (c31 & 15)));
#pragma unroll
        for (int rt = 0; rt < 2; rt++) {
            bf16x8 af = *(const bf16x8*)(woutb + (wv * 64 + rt * 32 + c31) * HID_ + k0);
            yacc[rt][0] = __builtin_amdgcn_mfma_f32_32x32x16_bf16(af, bq0, yacc[rt][0], 0, 0, 0);
            yacc[rt][1] = __builtin_amdgcn_mfma_f32_32x32x16_bf16(af, bq1, yacc[rt][1], 0, 0, 0);
        }
    }

    // ---- bias + RMS over c ----
#pragma unroll
    for (int rt = 0; rt < 2; rt++)
#pragma unroll
        for (int r = 0; r < 16; r++) {
            int rm = (r & 3) + 8 * (r >> 2) + 4 * hf;
            float bo = bl[wv * 64 + rt * 32 + rm];
            yacc[rt][0][r] += bo;
            yacc[rt][1][r] += bo;
        }
#pragma unroll
    for (int ct = 0; ct < 2; ct++) {
        float s = 0.f;
#pragma unroll
        for (int rt = 0; rt < 2; rt++)
#pragma unroll
            for (int r = 0; r < 16; r++) s = fmaf(yacc[rt][ct][r], yacc[rt][ct][r], s);
        s += __shfl_xor(s, 32);
        if (hf == 0) red[wv][ct * 32 + c31] = s;
    }
    __syncthreads();
    if (t < 64) {
        float S = red[0][t] + red[1][t] + red[2][t] + red[3][t];
        nrm[t] = 16.0f / fmaxf(sqrtf(S), 1e-12f);
    }
    __syncthreads();

    float* ob = out + (size_t)b * C_ * N_ + n0;
#pragma unroll
    for (int rt = 0; rt < 2; rt++)
#pragma unroll
        for (int r = 0; r < 16; r++) {
            int rm = (r & 3) + 8 * (r >> 2) + 4 * hf;
            int c  = wv * 64 + rt * 32 + rm;
            float gc = gl[c];
#pragma unroll
            for (int ct = 0; ct < 2; ct++) {
                int n = ct * 32 + c31;
                ob[(size_t)c * N_ + n] = yacc[rt][ct][r] * gc * nrm[n];
            }
        }
}

// ------------------------------------------------------------------
extern "C" void kernel_launch(void* const* d_in, const int* in_sizes, int n_in,
                              void* d_out, int out_size, void* d_ws, size_t ws_size,
                              hipStream_t stream)
{
    const float* x    = (const float*)d_in[0];
    const float* wqkv = (const float*)d_in[1];
    const float* wout = (const float*)d_in[2];
    const float* bout = (const float*)d_in[3];
    const float* g    = (const float*)d_in[4];
    float* out = (float*)d_out;

    // ws: qtb bf16 [B][N][HID] (32 MiB) | ctxacc f32 [B][H][D][33] | w bf16 [384*256 + 256*128]
    short* qtb    = (short*)d_ws;
    float* ctxacc = (float*)((char*)d_ws + (size_t)B_ * N_ * HID_ * 2);
    short* wbf    = (short*)((char*)ctxacc + (size_t)B_ * H_ * D_ * 33 * sizeof(float));
    short* woutb  = wbf + ROWS_ * C_;

    hipMemsetAsync(ctxacc, 0, (size_t)B_ * H_ * D_ * 33 * sizeof(float), stream);
    k_conv<<<(ROWS_ * C_ + C_ * HID_) / 1024, 256, 0, stream>>>(wqkv, wout, wbf);
    k_qkv<<<B_ * (N_ / 64), 256, 0, stream>>>(x, wbf, qtb, ctxacc);
    k_out<<<B_ * (N_ / 64), 256, 0, stream>>>(qtb, ctxacc, woutb, bout, g, out);
}